// Round 10
// baseline (68.152 us; speedup 1.0000x reference)
//
#include <hip/hip_runtime.h>
#include <math.h>

#define D 64
#define C 22
#define NCHUNK 64           // 256-teacher chunks (recovery granularity)
#define CHUNK 256
#define CPB 4               // chunks per nn block (reg-merged before 1 atomic)
#define NRANGE (NCHUNK / CPB)   // 16 chunk-ranges
#define SPT 2               // students per thread in nn role
#define TLP 24              // padded logit row (6 x float4)
#define SMEMF 1440          // max(C*D + C, 4*CHUNK) floats
#define TEMP_F 2.0f
#define KL_W_F 0.2f

// Shared helpers — single source so nn staging, tc4 prep, and loss-recovery
// compile to bit-identical chains.
__device__ __forceinline__ float4 prep_t(float x, float y, float z) {
    return make_float4(-2.f * x, -2.f * y, -2.f * z, fmaf(x, x, fmaf(y, y, z * z)));
}
__device__ __forceinline__ float dist_t(float sx, float sy, float sz,
                                        float tx, float ty, float tz, float tw) {
    // |t|^2 - 2 s.t   (|s|^2 constant per student: same argmin)
    return fmaf(sx, tx, fmaf(sy, ty, fmaf(sz, tz, tw)));
}
// Monotonic, bijective float->uint order transform (no NaNs here)
__device__ __forceinline__ unsigned int ord_of(float d) {
    unsigned int b = __float_as_uint(d);
    return (b & 0x80000000u) ? ~b : (b | 0x80000000u);
}

// 32-lane-group butterflies (offs <=16 keep lanes 0..31 self-contained)
__device__ __forceinline__ float bfly_max32(float v) {
#pragma unroll
    for (int off = 16; off; off >>= 1) v = fmaxf(v, __shfl_xor(v, off));
    return v;
}
__device__ __forceinline__ float bfly_sum32(float v) {
#pragma unroll
    for (int off = 16; off; off >>= 1) v += __shfl_xor(v, off);
    return v;
}

// ---------------------------------------------------------------- logits role body
__device__ __forceinline__ void logits_role(
        const float* __restrict__ feat, const float* __restrict__ W,
        const float* __restrict__ bias, float* __restrict__ olog,
        float* smem, int row0, int N)
{
    float* w = smem;                                   // C*D floats
    float* b = smem + C * D;
    for (int k = threadIdx.x; k < C * D; k += 256) w[k] = W[k];
    if (threadIdx.x < C) b[threadIdx.x] = bias[threadIdx.x];
    __syncthreads();

    int i = row0 + threadIdx.x;
    if (i >= N) return;

    float4 f[D / 4];
    const float4* fr = reinterpret_cast<const float4*>(feat + (size_t)i * D);
#pragma unroll
    for (int k = 0; k < D / 4; ++k) f[k] = fr[k];

    float* row = olog + (size_t)i * TLP;
#pragma unroll
    for (int c = 0; c < C; ++c) {
        float a = b[c];
        const float4* wr = reinterpret_cast<const float4*>(&w[c * D]);
#pragma unroll
        for (int k = 0; k < D / 4; ++k) {
            float4 wv = wr[k];
            a = fmaf(f[k].x, wv.x, a);
            a = fmaf(f[k].y, wv.y, a);
            a = fmaf(f[k].z, wv.z, a);
            a = fmaf(f[k].w, wv.w, a);
        }
        row[c] = a;
    }
}

// ================================================================ fat kernel
// role by blockIdx.x:  [0, nn_total)            -> 1-NN over CPB chunks -> atomicMin
//                      [nn_total, +ntb)         -> teacher logits + tc4 prep
//                      [nn_total+ntb, +nsb)     -> student logits
__global__ void __launch_bounds__(256) fat_kernel(
        const float* __restrict__ sc,      // [Ns][3]
        const float* __restrict__ tc,      // [Nt][3]
        const float* __restrict__ t_feat,  // [Nt][D]
        const float* __restrict__ s_feat,  // [Ns][D]
        const float* __restrict__ Wt, const float* __restrict__ bt,
        const float* __restrict__ Ws, const float* __restrict__ bs_,
        unsigned long long* __restrict__ cand64,  // [Ns] packed (ord(d)<<24)|chunk
        float4* __restrict__ tc4,          // [Nt] prepped (-2x,-2y,-2z,|t|^2)
        float*  __restrict__ tlog,         // [Nt][TLP]
        float*  __restrict__ slog,         // [Ns][TLP]
        float*  __restrict__ acc, unsigned* __restrict__ ct,
        int Ns, int Nt, int nn_total, int ntb)
{
    __shared__ __align__(16) float smem[SMEMF];
    const int bx = blockIdx.x;

    if (bx == 0 && threadIdx.x == 0) { acc[0] = 0.f; acc[1] = 0.f; *ct = 0u; }

    if (bx < nn_total) {
        // ------------- 1-NN role: CPB chunks, reg-merged, one atomic -------------
        float* xs = smem;
        float* ys = smem + CHUNK;
        float* zs = smem + 2 * CHUNK;
        float* ws = smem + 3 * CHUNK;
        const int crange = bx & (NRANGE - 1);          // 16 ranges
        const int sub    = bx >> 4;                    // log2(NRANGE)

        const int i0 = sub * (256 * SPT) + threadIdx.x;
        float sx[SPT], sy[SPT], sz[SPT], best[SPT];
        int   bk[SPT];
#pragma unroll
        for (int s = 0; s < SPT; ++s) {
            int i = i0 + s * 256;
            sx[s] = 0.f; sy[s] = 0.f; sz[s] = 0.f;
            best[s] = INFINITY; bk[s] = crange * CPB;
            if (i < Ns) {
                sx[s] = sc[(size_t)i * 3 + 0];
                sy[s] = sc[(size_t)i * 3 + 1];
                sz[s] = sc[(size_t)i * 3 + 2];
            }
        }

        for (int cc = 0; cc < CPB; ++cc) {
            const int chunk = crange * CPB + cc;
            const int base  = chunk * CHUNK;

            __syncthreads();                           // prior readers done
            {
                int j = threadIdx.x;                   // CHUNK == blockDim
                int g = base + j;
                float4 p;
                if (g < Nt) p = prep_t(tc[(size_t)g * 3 + 0], tc[(size_t)g * 3 + 1],
                                       tc[(size_t)g * 3 + 2]);
                else        p = make_float4(0.f, 0.f, 0.f, INFINITY);
                xs[j] = p.x; ys[j] = p.y; zs[j] = p.z; ws[j] = p.w;
            }
            __syncthreads();

            float cb[SPT];
#pragma unroll
            for (int s = 0; s < SPT; ++s) cb[s] = INFINITY;

#pragma unroll 4
            for (int j = 0; j < CHUNK; j += 4) {
                float4 X = *reinterpret_cast<const float4*>(&xs[j]);   // uniform:
                float4 Y = *reinterpret_cast<const float4*>(&ys[j]);   // broadcast
                float4 Z = *reinterpret_cast<const float4*>(&zs[j]);
                float4 W = *reinterpret_cast<const float4*>(&ws[j]);
#pragma unroll
                for (int s = 0; s < SPT; ++s) {
                    float d0 = dist_t(sx[s], sy[s], sz[s], X.x, Y.x, Z.x, W.x);
                    float d1 = dist_t(sx[s], sy[s], sz[s], X.y, Y.y, Z.y, W.y);
                    float d2 = dist_t(sx[s], sy[s], sz[s], X.z, Y.z, Z.z, W.z);
                    float d3 = dist_t(sx[s], sy[s], sz[s], X.w, Y.w, Z.w, W.w);
                    // right-nested: fuses to 2 x v_min3_f32
                    cb[s] = fminf(d0, fminf(d1, fminf(d2, fminf(d3, cb[s]))));
                }
            }
            // merge chunk-min into running (best, bk); strict <: earliest chunk
#pragma unroll
            for (int s = 0; s < SPT; ++s) {
                bool c = cb[s] < best[s];
                best[s] = c ? cb[s] : best[s];
                bk[s]   = c ? chunk : bk[s];
            }
        }
        // one lexicographic-packed atomic per student (order-independent)
#pragma unroll
        for (int s = 0; s < SPT; ++s) {
            int i = i0 + s * 256;
            if (i < Ns) {
                unsigned long long pk =
                    ((unsigned long long)ord_of(best[s]) << 24) | (unsigned)bk[s];
                atomicMin(&cand64[i], pk);
            }
        }
    } else if (bx < nn_total + ntb) {
        // teacher logits + tc4 prep
        int i = (bx - nn_total) * 256 + threadIdx.x;
        if (i < Nt)
            tc4[i] = prep_t(tc[(size_t)i * 3 + 0], tc[(size_t)i * 3 + 1],
                            tc[(size_t)i * 3 + 2]);
        logits_role(t_feat, Wt, bt, tlog, smem, (bx - nn_total) * 256, Nt);
    } else {
        logits_role(s_feat, Ws, bs_, slog, smem, (bx - nn_total - ntb) * 256, Ns);
    }
}

// ================================================================ loss (+finalize)
// 512 blocks x 1024 threads = 8192 waves (full 32 waves/CU). Wave per student
// iteration (2 each). Phase 1: single 8B packed load. Phase 2: 64-lane scan of
// winning chunk (bit-exact match). Phase 3: class-parallel math on lanes 0..21.
__global__ void __launch_bounds__(1024) loss_kernel(
        const float* __restrict__ sc,       // [Ns][3]
        const int*   __restrict__ segment,  // [Ns]
        const float* __restrict__ tlog,     // [Nt][TLP]
        const float* __restrict__ slog,     // [Ns][TLP]
        const unsigned long long* __restrict__ cand64,  // [Ns]
        const float4* __restrict__ tc4,     // [Nt]
        float* __restrict__ acc, unsigned* __restrict__ ct,
        float* __restrict__ out, int Ns)
{
    __shared__ float rs[16], rk[16];
    const int lane   = threadIdx.x & 63;
    const int wv     = threadIdx.x >> 6;              // 0..15
    const int nwaves = gridDim.x * 16;

    float seg_a = 0.f, kl_a = 0.f;

    for (int i = blockIdx.x * 16 + wv; i < Ns; i += nwaves) {
        // ---- phase 1: unpack winner (value-order, earliest chunk)
        unsigned long long pk = cand64[i];
        const int k = (int)(pk & 0xFFFFFFu);
        const unsigned int ub = (unsigned int)(pk >> 24);
        // inverse order-transform -> exact float bits of the winning distance
        const unsigned int bbits = (ub & 0x80000000u) ? (ub & 0x7FFFFFFFu) : ~ub;

        // ---- phase 2: recover within-chunk index (bit-exact recompute)
        float sx = sc[(size_t)i * 3 + 0];
        float sy = sc[(size_t)i * 3 + 1];
        float sz = sc[(size_t)i * 3 + 2];
        const float4* P = tc4 + (size_t)k * CHUNK;
        int fj = 0x7fffffff;
#pragma unroll
        for (int t = 0; t < CHUNK / 64; ++t) {
            int j = lane + t * 64;                 // coalesced float4 across wave
            float4 p = P[j];
            float d = dist_t(sx, sy, sz, p.x, p.y, p.z, p.w);
            if (__float_as_uint(d) == bbits && j < fj) fj = j;
        }
#pragma unroll
        for (int off = 32; off; off >>= 1)
            fj = min(fj, __shfl_xor(fj, off));
        if (fj == 0x7fffffff) fj = 0;              // unreachable fallback
        const int bidx = k * CHUNK + fj;

        // ---- phase 3: class-parallel CE + KL (lanes 0..21)
        float lv = -INFINITY, tv = -INFINITY;
        if (lane < C) {
            lv = slog[(size_t)i * TLP + lane];
            tv = tlog[(size_t)bidx * TLP + lane];
        }
        float m1 = bfly_max32(lv);
        float mt = bfly_max32(tv);

        float dlc = lv - m1;                       // lane >= C: -INF (never read)
        float e1 = 0.f, e2 = 0.f, u = 0.f, Tc = 0.f;
        if (lane < C) {
            e1 = expf(dlc);
            e2 = expf(0.5f * dlc);
            float du = tv - mt;
            u  = expf(0.5f * du);
            Tc = u * 0.5f * (du - dlc);
        }
        float sum1 = bfly_sum32(e1);
        float sum2 = bfly_sum32(e2);
        float U    = bfly_sum32(u);
        float T    = bfly_sum32(Tc);
        int   sg   = segment[i];
        float lsg  = __shfl(dlc, sg);              // broadcast from lane sg

        // valid on lanes 0..31; harvested from lane 0 only
        seg_a += logf(sum1) - lsg;
        kl_a  += T / U + logf(sum2) - logf(U);
    }

    // ---- block reduce from each wave's lane 0, one atomic pair per block
    if (lane == 0) { rs[wv] = seg_a; rk[wv] = kl_a; }
    __syncthreads();
    if (threadIdx.x == 0) {
        float s = 0.f, kk = 0.f;
#pragma unroll
        for (int w = 0; w < 16; ++w) { s += rs[w]; kk += rk[w]; }
        atomicAdd(&acc[0], s);
        atomicAdd(&acc[1], kk);
        __threadfence();
        unsigned t = atomicAdd(ct, 1u);
        if (t == gridDim.x - 1) {
            float seg = atomicAdd(&acc[0], 0.f);   // coherent read
            float kl  = atomicAdd(&acc[1], 0.f);
            float seg_loss = seg / (float)Ns;
            float kl_loss  = KL_W_F * (kl / (float)Ns) * TEMP_F * TEMP_F;
            out[0] = seg_loss + kl_loss;
            out[1] = seg_loss;
            out[2] = kl_loss;
        }
    }
}

extern "C" void kernel_launch(void* const* d_in, const int* in_sizes, int n_in,
                              void* d_out, int out_size, void* d_ws, size_t ws_size,
                              hipStream_t stream)
{
    const float* s_feat  = (const float*)d_in[0];
    const float* t_feat  = (const float*)d_in[1];
    const float* s_coord = (const float*)d_in[2];
    const float* t_coord = (const float*)d_in[3];
    const float* seg_W   = (const float*)d_in[4];
    const float* seg_b   = (const float*)d_in[5];
    const float* seg_tW  = (const float*)d_in[6];
    const float* seg_tb  = (const float*)d_in[7];
    const int*   segment = (const int*)d_in[8];
    float* out = (float*)d_out;

    const int Ns = in_sizes[0] / D;
    const int Nt = in_sizes[1] / D;

    float* tlog = (float*)d_ws;                                        // [Nt*TLP]
    float* slog = tlog + (size_t)Nt * TLP;                             // [Ns*TLP]
    unsigned long long* cand64 =
        (unsigned long long*)(slog + (size_t)Ns * TLP);                // [Ns]
    float4* tc4 = (float4*)(cand64 + Ns);                              // [Nt]
    float*  acc = (float*)(tc4 + Nt);                                  // [2]
    unsigned* ct = (unsigned*)(acc + 2);

    // init packed candidates to +max (order-independent atomicMin target)
    hipMemsetAsync(cand64, 0xFF, (size_t)Ns * sizeof(unsigned long long), stream);

    const int subs     = (Ns + 256 * SPT - 1) / (256 * SPT);           // 32
    const int nn_total = subs * NRANGE;                                // 512
    const int ntb      = (Nt + 255) / 256;                             // 64
    const int nsb      = (Ns + 255) / 256;                             // 64

    fat_kernel<<<nn_total + ntb + nsb, 256, 0, stream>>>(
        s_coord, t_coord, t_feat, s_feat, seg_tW, seg_tb, seg_W, seg_b,
        cand64, tc4, tlog, slog, acc, ct, Ns, Nt, nn_total, ntb);

    loss_kernel<<<512, 1024, 0, stream>>>(
        s_coord, segment, tlog, slog, cand64, tc4, acc, ct, out, Ns);
}

// Round 11
// 65.814 us; speedup vs baseline: 1.0355x; 1.0355x over previous
//
#include <hip/hip_runtime.h>
#include <math.h>

#define D 64
#define C 22
#define NCHUNK 64           // 256-teacher chunks (recovery granularity)
#define CHUNK 256
#define CPB 2               // chunks per nn block (reg-merged, one store)
#define NRANGE (NCHUNK / CPB)   // 32 chunk-ranges = packed entries per student
#define SPT 2               // students per thread in nn role
#define TLP 24              // padded logit row (6 x float4)
#define SMEMF 1440          // max(C*D + C, 4*CHUNK) floats
#define TEMP_F 2.0f
#define KL_W_F 0.2f

// Shared helpers — single source so nn staging, tc4 prep, and loss-recovery
// compile to bit-identical chains.
__device__ __forceinline__ float4 prep_t(float x, float y, float z) {
    return make_float4(-2.f * x, -2.f * y, -2.f * z, fmaf(x, x, fmaf(y, y, z * z)));
}
__device__ __forceinline__ float dist_t(float sx, float sy, float sz,
                                        float tx, float ty, float tz, float tw) {
    // |t|^2 - 2 s.t   (|s|^2 constant per student: same argmin)
    return fmaf(sx, tx, fmaf(sy, ty, fmaf(sz, tz, tw)));
}
// Monotonic, bijective float->uint order transform (no NaNs here)
__device__ __forceinline__ unsigned int ord_of(float d) {
    unsigned int b = __float_as_uint(d);
    return (b & 0x80000000u) ? ~b : (b | 0x80000000u);
}

// 32-lane-group butterflies (offs <=16 keep lanes 0..31 self-contained)
__device__ __forceinline__ float bfly_max32(float v) {
#pragma unroll
    for (int off = 16; off; off >>= 1) v = fmaxf(v, __shfl_xor(v, off));
    return v;
}
__device__ __forceinline__ float bfly_sum32(float v) {
#pragma unroll
    for (int off = 16; off; off >>= 1) v += __shfl_xor(v, off);
    return v;
}

// ---------------------------------------------------------------- logits role body
__device__ __forceinline__ void logits_role(
        const float* __restrict__ feat, const float* __restrict__ W,
        const float* __restrict__ bias, float* __restrict__ olog,
        float* smem, int row0, int N)
{
    float* w = smem;                                   // C*D floats
    float* b = smem + C * D;
    for (int k = threadIdx.x; k < C * D; k += 256) w[k] = W[k];
    if (threadIdx.x < C) b[threadIdx.x] = bias[threadIdx.x];
    __syncthreads();

    int i = row0 + threadIdx.x;
    if (i >= N) return;

    float4 f[D / 4];
    const float4* fr = reinterpret_cast<const float4*>(feat + (size_t)i * D);
#pragma unroll
    for (int k = 0; k < D / 4; ++k) f[k] = fr[k];

    float* row = olog + (size_t)i * TLP;
#pragma unroll
    for (int c = 0; c < C; ++c) {
        float a = b[c];
        const float4* wr = reinterpret_cast<const float4*>(&w[c * D]);
#pragma unroll
        for (int k = 0; k < D / 4; ++k) {
            float4 wv = wr[k];
            a = fmaf(f[k].x, wv.x, a);
            a = fmaf(f[k].y, wv.y, a);
            a = fmaf(f[k].z, wv.z, a);
            a = fmaf(f[k].w, wv.w, a);
        }
        row[c] = a;
    }
}

// ================================================================ fat kernel
// role by blockIdx.x:  [0, nn_total)        -> 1-NN over CPB chunks -> 1 packed store
//                      [nn_total, +ntb)     -> teacher logits + tc4 prep
//                      [nn_total+ntb, +nsb) -> student logits
__global__ void __launch_bounds__(256) fat_kernel(
        const float* __restrict__ sc,      // [Ns][3]
        const float* __restrict__ tc,      // [Nt][3]
        const float* __restrict__ t_feat,  // [Nt][D]
        const float* __restrict__ s_feat,  // [Ns][D]
        const float* __restrict__ Wt, const float* __restrict__ bt,
        const float* __restrict__ Ws, const float* __restrict__ bs_,
        unsigned long long* __restrict__ cand_pk,  // [NRANGE][Ns] chunk-major
        float4* __restrict__ tc4,          // [Nt] prepped (-2x,-2y,-2z,|t|^2)
        float*  __restrict__ tlog,         // [Nt][TLP]
        float*  __restrict__ slog,         // [Ns][TLP]
        float*  __restrict__ acc, unsigned* __restrict__ ct,
        int Ns, int Nt, int nn_total, int ntb)
{
    __shared__ __align__(16) float smem[SMEMF];
    const int bx = blockIdx.x;

    if (bx == 0 && threadIdx.x == 0) { acc[0] = 0.f; acc[1] = 0.f; *ct = 0u; }

    if (bx < nn_total) {
        // ------------- 1-NN role: CPB chunks, reg-merged, one plain store -------------
        float* xs = smem;
        float* ys = smem + CHUNK;
        float* zs = smem + 2 * CHUNK;
        float* ws = smem + 3 * CHUNK;
        const int crange = bx & (NRANGE - 1);          // 32 ranges
        const int sub    = bx >> 5;                    // log2(NRANGE)

        const int i0 = sub * (256 * SPT) + threadIdx.x;
        float sx[SPT], sy[SPT], sz[SPT], best[SPT];
        int   bk[SPT];
#pragma unroll
        for (int s = 0; s < SPT; ++s) {
            int i = i0 + s * 256;
            sx[s] = 0.f; sy[s] = 0.f; sz[s] = 0.f;
            best[s] = INFINITY; bk[s] = crange * CPB;
            if (i < Ns) {
                sx[s] = sc[(size_t)i * 3 + 0];
                sy[s] = sc[(size_t)i * 3 + 1];
                sz[s] = sc[(size_t)i * 3 + 2];
            }
        }

        for (int cc = 0; cc < CPB; ++cc) {
            const int chunk = crange * CPB + cc;
            const int base  = chunk * CHUNK;

            __syncthreads();                           // prior readers done
            {
                int j = threadIdx.x;                   // CHUNK == blockDim
                int g = base + j;
                float4 p;
                if (g < Nt) p = prep_t(tc[(size_t)g * 3 + 0], tc[(size_t)g * 3 + 1],
                                       tc[(size_t)g * 3 + 2]);
                else        p = make_float4(0.f, 0.f, 0.f, INFINITY);
                xs[j] = p.x; ys[j] = p.y; zs[j] = p.z; ws[j] = p.w;
            }
            __syncthreads();

            float cb[SPT];
#pragma unroll
            for (int s = 0; s < SPT; ++s) cb[s] = INFINITY;

#pragma unroll 4
            for (int j = 0; j < CHUNK; j += 4) {
                float4 X = *reinterpret_cast<const float4*>(&xs[j]);   // uniform:
                float4 Y = *reinterpret_cast<const float4*>(&ys[j]);   // broadcast
                float4 Z = *reinterpret_cast<const float4*>(&zs[j]);
                float4 W = *reinterpret_cast<const float4*>(&ws[j]);
#pragma unroll
                for (int s = 0; s < SPT; ++s) {
                    float d0 = dist_t(sx[s], sy[s], sz[s], X.x, Y.x, Z.x, W.x);
                    float d1 = dist_t(sx[s], sy[s], sz[s], X.y, Y.y, Z.y, W.y);
                    float d2 = dist_t(sx[s], sy[s], sz[s], X.z, Y.z, Z.z, W.z);
                    float d3 = dist_t(sx[s], sy[s], sz[s], X.w, Y.w, Z.w, W.w);
                    // right-nested: fuses to 2 x v_min3_f32
                    cb[s] = fminf(d0, fminf(d1, fminf(d2, fminf(d3, cb[s]))));
                }
            }
            // merge chunk-min into running (best, bk); strict <: earliest chunk
#pragma unroll
            for (int s = 0; s < SPT; ++s) {
                bool c = cb[s] < best[s];
                best[s] = c ? cb[s] : best[s];
                bk[s]   = c ? chunk : bk[s];
            }
        }
        // one coalesced packed store per student per range (no init, no atomics)
#pragma unroll
        for (int s = 0; s < SPT; ++s) {
            int i = i0 + s * 256;
            if (i < Ns) {
                unsigned long long pk =
                    ((unsigned long long)ord_of(best[s]) << 24) | (unsigned)bk[s];
                cand_pk[(size_t)crange * Ns + i] = pk;
            }
        }
    } else if (bx < nn_total + ntb) {
        // teacher logits + tc4 prep
        int i = (bx - nn_total) * 256 + threadIdx.x;
        if (i < Nt)
            tc4[i] = prep_t(tc[(size_t)i * 3 + 0], tc[(size_t)i * 3 + 1],
                            tc[(size_t)i * 3 + 2]);
        logits_role(t_feat, Wt, bt, tlog, smem, (bx - nn_total) * 256, Nt);
    } else {
        logits_role(s_feat, Ws, bs_, slog, smem, (bx - nn_total - ntb) * 256, Ns);
    }
}

// ================================================================ loss (+finalize)
// 512 blocks x 1024 threads = 8192 waves (full 32 waves/CU). Wave per student
// iteration (2 each). Phase 1: lanes 0..31 load packed range minima, u64
// butterfly min (lexicographic = smallest dist, earliest chunk). Phase 2:
// 64-lane scan of winning chunk (bit-exact). Phase 3: class-parallel lanes 0..21.
__global__ void __launch_bounds__(1024) loss_kernel(
        const float* __restrict__ sc,       // [Ns][3]
        const int*   __restrict__ segment,  // [Ns]
        const float* __restrict__ tlog,     // [Nt][TLP]
        const float* __restrict__ slog,     // [Ns][TLP]
        const unsigned long long* __restrict__ cand_pk,  // [NRANGE][Ns]
        const float4* __restrict__ tc4,     // [Nt]
        float* __restrict__ acc, unsigned* __restrict__ ct,
        float* __restrict__ out, int Ns)
{
    __shared__ float rs[16], rk[16];
    const int lane   = threadIdx.x & 63;
    const int wv     = threadIdx.x >> 6;              // 0..15
    const int nwaves = gridDim.x * 16;

    float seg_a = 0.f, kl_a = 0.f;

    for (int i = blockIdx.x * 16 + wv; i < Ns; i += nwaves) {
        // ---- phase 1: packed range minima + u64 butterfly min
        unsigned long long pk = (lane < NRANGE)
            ? cand_pk[(size_t)lane * Ns + i] : ~0ULL;
#pragma unroll
        for (int off = 32; off; off >>= 1) {
            unsigned long long po = __shfl_xor(pk, off);
            pk = (po < pk) ? po : pk;
        }
        const int k = (int)(pk & 0xFFFFFFu);
        const unsigned int ub = (unsigned int)(pk >> 24);
        // inverse order-transform -> exact float bits of the winning distance
        const unsigned int bbits = (ub & 0x80000000u) ? (ub & 0x7FFFFFFFu) : ~ub;

        // ---- phase 2: recover within-chunk index (bit-exact recompute)
        float sx = sc[(size_t)i * 3 + 0];
        float sy = sc[(size_t)i * 3 + 1];
        float sz = sc[(size_t)i * 3 + 2];
        const float4* P = tc4 + (size_t)k * CHUNK;
        int fj = 0x7fffffff;
#pragma unroll
        for (int t = 0; t < CHUNK / 64; ++t) {
            int j = lane + t * 64;                 // coalesced float4 across wave
            float4 p = P[j];
            float d = dist_t(sx, sy, sz, p.x, p.y, p.z, p.w);
            if (__float_as_uint(d) == bbits && j < fj) fj = j;
        }
#pragma unroll
        for (int off = 32; off; off >>= 1)
            fj = min(fj, __shfl_xor(fj, off));
        if (fj == 0x7fffffff) fj = 0;              // unreachable fallback
        const int bidx = k * CHUNK + fj;

        // ---- phase 3: class-parallel CE + KL (lanes 0..21)
        float lv = -INFINITY, tv = -INFINITY;
        if (lane < C) {
            lv = slog[(size_t)i * TLP + lane];
            tv = tlog[(size_t)bidx * TLP + lane];
        }
        float m1 = bfly_max32(lv);
        float mt = bfly_max32(tv);

        float dlc = lv - m1;                       // lane >= C: -INF (never read)
        float e1 = 0.f, e2 = 0.f, u = 0.f, Tc = 0.f;
        if (lane < C) {
            e1 = expf(dlc);
            e2 = expf(0.5f * dlc);
            float du = tv - mt;
            u  = expf(0.5f * du);
            Tc = u * 0.5f * (du - dlc);
        }
        float sum1 = bfly_sum32(e1);
        float sum2 = bfly_sum32(e2);
        float U    = bfly_sum32(u);
        float T    = bfly_sum32(Tc);
        int   sg   = segment[i];
        float lsg  = __shfl(dlc, sg);              // broadcast from lane sg

        // valid on lanes 0..31; harvested from lane 0 only
        seg_a += logf(sum1) - lsg;
        kl_a  += T / U + logf(sum2) - logf(U);
    }

    // ---- block reduce from each wave's lane 0, one atomic pair per block
    if (lane == 0) { rs[wv] = seg_a; rk[wv] = kl_a; }
    __syncthreads();
    if (threadIdx.x == 0) {
        float s = 0.f, kk = 0.f;
#pragma unroll
        for (int w = 0; w < 16; ++w) { s += rs[w]; kk += rk[w]; }
        atomicAdd(&acc[0], s);
        atomicAdd(&acc[1], kk);
        __threadfence();
        unsigned t = atomicAdd(ct, 1u);
        if (t == gridDim.x - 1) {
            float seg = atomicAdd(&acc[0], 0.f);   // coherent read
            float kl  = atomicAdd(&acc[1], 0.f);
            float seg_loss = seg / (float)Ns;
            float kl_loss  = KL_W_F * (kl / (float)Ns) * TEMP_F * TEMP_F;
            out[0] = seg_loss + kl_loss;
            out[1] = seg_loss;
            out[2] = kl_loss;
        }
    }
}

extern "C" void kernel_launch(void* const* d_in, const int* in_sizes, int n_in,
                              void* d_out, int out_size, void* d_ws, size_t ws_size,
                              hipStream_t stream)
{
    const float* s_feat  = (const float*)d_in[0];
    const float* t_feat  = (const float*)d_in[1];
    const float* s_coord = (const float*)d_in[2];
    const float* t_coord = (const float*)d_in[3];
    const float* seg_W   = (const float*)d_in[4];
    const float* seg_b   = (const float*)d_in[5];
    const float* seg_tW  = (const float*)d_in[6];
    const float* seg_tb  = (const float*)d_in[7];
    const int*   segment = (const int*)d_in[8];
    float* out = (float*)d_out;

    const int Ns = in_sizes[0] / D;
    const int Nt = in_sizes[1] / D;

    float* tlog = (float*)d_ws;                                        // [Nt*TLP]
    float* slog = tlog + (size_t)Nt * TLP;                             // [Ns*TLP]
    unsigned long long* cand_pk =
        (unsigned long long*)(slog + (size_t)Ns * TLP);                // [NRANGE*Ns]
    float4* tc4 = (float4*)(cand_pk + (size_t)NRANGE * Ns);            // [Nt]
    float*  acc = (float*)(tc4 + Nt);                                  // [2]
    unsigned* ct = (unsigned*)(acc + 2);

    const int subs     = (Ns + 256 * SPT - 1) / (256 * SPT);           // 32
    const int nn_total = subs * NRANGE;                                // 1024
    const int ntb      = (Nt + 255) / 256;                             // 64
    const int nsb      = (Ns + 255) / 256;                             // 64

    fat_kernel<<<nn_total + ntb + nsb, 256, 0, stream>>>(
        s_coord, t_coord, t_feat, s_feat, seg_tW, seg_tb, seg_W, seg_b,
        cand_pk, tc4, tlog, slog, acc, ct, Ns, Nt, nn_total, ntb);

    loss_kernel<<<512, 1024, 0, stream>>>(
        s_coord, segment, tlog, slog, cand_pk, tc4, acc, ct, out, Ns);
}

// Round 12
// 64.346 us; speedup vs baseline: 1.0592x; 1.0228x over previous
//
#include <hip/hip_runtime.h>
#include <math.h>

#define D 64
#define C 22
#define NCHUNK 64           // one chunk per nn block; == wave width in loss
#define CHUNK 256
#define SPT 8               // students per thread in nn role (LDS amortization)
#define TLP 24              // padded logit row (6 x float4)
#define SMEMF 1440          // max(C*D + C, 4*CHUNK) floats
#define TEMP_F 2.0f
#define KL_W_F 0.2f

// Shared helpers — single source so nn staging, tc4 prep, and loss-recovery
// compile to bit-identical chains.
__device__ __forceinline__ float4 prep_t(float x, float y, float z) {
    return make_float4(-2.f * x, -2.f * y, -2.f * z, fmaf(x, x, fmaf(y, y, z * z)));
}
__device__ __forceinline__ float dist_t(float sx, float sy, float sz,
                                        float tx, float ty, float tz, float tw) {
    // |t|^2 - 2 s.t   (|s|^2 constant per student: same argmin)
    return fmaf(sx, tx, fmaf(sy, ty, fmaf(sz, tz, tw)));
}
// Monotonic, bijective float->uint order transform (no NaNs here)
__device__ __forceinline__ unsigned ord_of(float d) {
    unsigned b = __float_as_uint(d);
    return (b & 0x80000000u) ? ~b : (b | 0x80000000u);
}

__device__ __forceinline__ float bfly_max32(float v) {
#pragma unroll
    for (int off = 16; off; off >>= 1) v = fmaxf(v, __shfl_xor(v, off));
    return v;
}
__device__ __forceinline__ float bfly_sum32(float v) {
#pragma unroll
    for (int off = 16; off; off >>= 1) v += __shfl_xor(v, off);
    return v;
}
__device__ __forceinline__ unsigned bfly_min64u(unsigned v) {
#pragma unroll
    for (int off = 32; off; off >>= 1) {
        unsigned o = (unsigned)__shfl_xor((int)v, off);
        v = (o < v) ? o : v;
    }
    return v;
}

// ---------------------------------------------------------------- logits role body
__device__ __forceinline__ void logits_role(
        const float* __restrict__ feat, const float* __restrict__ W,
        const float* __restrict__ bias, float* __restrict__ olog,
        float* smem, int row0, int N)
{
    float* w = smem;                                   // C*D floats
    float* b = smem + C * D;
    for (int k = threadIdx.x; k < C * D; k += 256) w[k] = W[k];
    if (threadIdx.x < C) b[threadIdx.x] = bias[threadIdx.x];
    __syncthreads();

    int i = row0 + threadIdx.x;
    if (i >= N) return;

    float4 f[D / 4];
    const float4* fr = reinterpret_cast<const float4*>(feat + (size_t)i * D);
#pragma unroll
    for (int k = 0; k < D / 4; ++k) f[k] = fr[k];

    float* row = olog + (size_t)i * TLP;
#pragma unroll
    for (int c = 0; c < C; ++c) {
        float a = b[c];
        const float4* wr = reinterpret_cast<const float4*>(&w[c * D]);
#pragma unroll
        for (int k = 0; k < D / 4; ++k) {
            float4 wv = wr[k];
            a = fmaf(f[k].x, wv.x, a);
            a = fmaf(f[k].y, wv.y, a);
            a = fmaf(f[k].z, wv.z, a);
            a = fmaf(f[k].w, wv.w, a);
        }
        row[c] = a;
    }
}

// ================================================================ fat kernel
// role by blockIdx.x:  [0, nn_total)        -> 1-NN chunk min -> 4B ord store
//                      [nn_total, +ntb)     -> teacher logits + tc4 prep
//                      [nn_total+ntb, +nsb) -> student logits
__global__ void __launch_bounds__(256) fat_kernel(
        const float* __restrict__ sc,      // [Ns][3]
        const float* __restrict__ tc,      // [Nt][3]
        const float* __restrict__ t_feat,  // [Nt][D]
        const float* __restrict__ s_feat,  // [Ns][D]
        const float* __restrict__ Wt, const float* __restrict__ bt,
        const float* __restrict__ Ws, const float* __restrict__ bs_,
        unsigned* __restrict__ cand_ord,   // [NCHUNK][Ns] chunk-major, 4B
        float4* __restrict__ tc4,          // [Nt] prepped (-2x,-2y,-2z,|t|^2)
        float*  __restrict__ tlog,         // [Nt][TLP]
        float*  __restrict__ slog,         // [Ns][TLP]
        float*  __restrict__ acc, unsigned* __restrict__ ct,
        int Ns, int Nt, int nn_total, int ntb)
{
    __shared__ __align__(16) float smem[SMEMF];
    const int bx = blockIdx.x;

    if (bx == 0 && threadIdx.x == 0) { acc[0] = 0.f; acc[1] = 0.f; *ct = 0u; }

    if (bx < nn_total) {
        // ---- 1-NN role: one chunk, 8 students/thread, SoA LDS ----
        float* xs = smem;
        float* ys = smem + CHUNK;
        float* zs = smem + 2 * CHUNK;
        float* ws = smem + 3 * CHUNK;
        const int chunk = bx & (NCHUNK - 1);           // 64 chunks
        const int sub   = bx >> 6;
        const int base  = chunk * CHUNK;

        {
            int j = threadIdx.x;                       // CHUNK == blockDim
            int g = base + j;
            float4 p;
            if (g < Nt) p = prep_t(tc[(size_t)g * 3 + 0], tc[(size_t)g * 3 + 1],
                                   tc[(size_t)g * 3 + 2]);
            else        p = make_float4(0.f, 0.f, 0.f, INFINITY);
            xs[j] = p.x; ys[j] = p.y; zs[j] = p.z; ws[j] = p.w;
        }
        __syncthreads();

        const int i0 = sub * (256 * SPT) + threadIdx.x;
        float sx[SPT], sy[SPT], sz[SPT], best[SPT];
#pragma unroll
        for (int s = 0; s < SPT; ++s) {
            int i = i0 + s * 256;
            sx[s] = 0.f; sy[s] = 0.f; sz[s] = 0.f; best[s] = INFINITY;
            if (i < Ns) {
                sx[s] = sc[(size_t)i * 3 + 0];
                sy[s] = sc[(size_t)i * 3 + 1];
                sz[s] = sc[(size_t)i * 3 + 2];
            }
        }

#pragma unroll 2
        for (int j = 0; j < CHUNK; j += 4) {
            float4 X = *reinterpret_cast<const float4*>(&xs[j]);   // uniform addr:
            float4 Y = *reinterpret_cast<const float4*>(&ys[j]);   // LDS broadcast
            float4 Z = *reinterpret_cast<const float4*>(&zs[j]);
            float4 W = *reinterpret_cast<const float4*>(&ws[j]);
#pragma unroll
            for (int s = 0; s < SPT; ++s) {
                float d0 = dist_t(sx[s], sy[s], sz[s], X.x, Y.x, Z.x, W.x);
                float d1 = dist_t(sx[s], sy[s], sz[s], X.y, Y.y, Z.y, W.y);
                float d2 = dist_t(sx[s], sy[s], sz[s], X.z, Y.z, Z.z, W.z);
                float d3 = dist_t(sx[s], sy[s], sz[s], X.w, Y.w, Z.w, W.w);
                // right-nested: fuses to 2 x v_min3_f32
                best[s] = fminf(d0, fminf(d1, fminf(d2, fminf(d3, best[s]))));
            }
        }
        // coalesced 4B ord stores (each entry written exactly once; no init)
#pragma unroll
        for (int s = 0; s < SPT; ++s) {
            int i = i0 + s * 256;
            if (i < Ns) cand_ord[(size_t)chunk * Ns + i] = ord_of(best[s]);
        }
    } else if (bx < nn_total + ntb) {
        // teacher logits + tc4 prep
        int i = (bx - nn_total) * 256 + threadIdx.x;
        if (i < Nt)
            tc4[i] = prep_t(tc[(size_t)i * 3 + 0], tc[(size_t)i * 3 + 1],
                            tc[(size_t)i * 3 + 2]);
        logits_role(t_feat, Wt, bt, tlog, smem, (bx - nn_total) * 256, Nt);
    } else {
        logits_role(s_feat, Ws, bs_, slog, smem, (bx - nn_total - ntb) * 256, Ns);
    }
}

// ================================================================ loss (+finalize)
// 512 blocks x 1024 threads = 8192 waves (full 32 waves/CU), wave/student.
// Phase 1: lane k = chunk k's ord; 64-lane min + ballot -> earliest min chunk.
// Phase 2: 64-lane bit-exact rescan of winning chunk. Phase 3: split halves —
// lanes 0..31 student softmax, lanes 32..63 teacher softmax, in parallel.
__global__ void __launch_bounds__(1024) loss_kernel(
        const float* __restrict__ sc,       // [Ns][3]
        const int*   __restrict__ segment,  // [Ns]
        const float* __restrict__ tlog,     // [Nt][TLP]
        const float* __restrict__ slog,     // [Ns][TLP]
        const unsigned* __restrict__ cand_ord,  // [NCHUNK][Ns]
        const float4* __restrict__ tc4,     // [Nt]
        float* __restrict__ acc, unsigned* __restrict__ ct,
        float* __restrict__ out, int Ns)
{
    __shared__ float rs[16], rk[16];
    const int lane   = threadIdx.x & 63;
    const int wv     = threadIdx.x >> 6;              // 0..15
    const int nwaves = gridDim.x * 16;

    float seg_a = 0.f, kl_a = 0.f;

    for (int i = blockIdx.x * 16 + wv; i < Ns; i += nwaves) {
        // ---- phase 1: 64 chunk ords -> min + earliest-chunk ballot
        unsigned o  = cand_ord[(size_t)lane * Ns + i];
        unsigned mo = bfly_min64u(o);
        unsigned long long msk = __ballot(o == mo);
        const int k = __ffsll(msk) - 1;               // earliest min chunk
        // inverse order-transform -> exact float bits of the winning distance
        const unsigned bbits = (mo & 0x80000000u) ? (mo & 0x7FFFFFFFu) : ~mo;

        // ---- phase 2: recover within-chunk index (bit-exact recompute)
        float sx = sc[(size_t)i * 3 + 0];
        float sy = sc[(size_t)i * 3 + 1];
        float sz = sc[(size_t)i * 3 + 2];
        const float4* P = tc4 + (size_t)k * CHUNK;
        int fj = 0x7fffffff;
#pragma unroll
        for (int t = 0; t < CHUNK / 64; ++t) {
            int j = lane + t * 64;                 // coalesced float4 across wave
            float4 p = P[j];
            float d = dist_t(sx, sy, sz, p.x, p.y, p.z, p.w);
            if (__float_as_uint(d) == bbits && j < fj) fj = j;
        }
#pragma unroll
        for (int off = 32; off; off >>= 1)
            fj = min(fj, __shfl_xor(fj, off));
        if (fj == 0x7fffffff) fj = 0;              // unreachable fallback
        const int bidx = k * CHUNK + fj;

        // ---- phase 3: split halves (student: lanes 0..31, teacher: 32..63)
        const int half = lane >> 5;
        const int c    = lane & 31;
        float val = -INFINITY;
        if (c < C) val = half ? tlog[(size_t)bidx * TLP + c]
                              : slog[(size_t)i * TLP + c];
        float m  = bfly_max32(val);                // m1 (lower) / mt (upper)
        float dv = val - m;                        // dlc (lower) / du (upper)
        float dlc_u = __shfl(dv, c);               // lower-half dlc, broadcast up

        float a0 = 0.f, a1 = 0.f;
        if (c < C) {
            if (half) {                            // teacher: u, Tc
                float u = expf(0.5f * dv);
                a0 = u;
                a1 = u * 0.5f * (dv - dlc_u);
            } else {                               // student: e1, e2
                a0 = expf(dv);
                a1 = expf(0.5f * dv);
            }
        }
        float s0 = bfly_sum32(a0);                 // sum1 (lower) / U (upper)
        float s1 = bfly_sum32(a1);                 // sum2 (lower) / T (upper)
        float U  = __shfl(s0, 32);
        float T  = __shfl(s1, 32);
        int   sg = segment[i];
        float lsg = __shfl(dv, sg);                // from lower half lane sg

        // valid on lane 0 only (harvested there)
        seg_a += logf(s0) - lsg;
        kl_a  += T / U + logf(s1) - logf(U);
    }

    // ---- block reduce from each wave's lane 0, one atomic pair per block
    if (lane == 0) { rs[wv] = seg_a; rk[wv] = kl_a; }
    __syncthreads();
    if (threadIdx.x == 0) {
        float s = 0.f, kk = 0.f;
#pragma unroll
        for (int w = 0; w < 16; ++w) { s += rs[w]; kk += rk[w]; }
        atomicAdd(&acc[0], s);
        atomicAdd(&acc[1], kk);
        __threadfence();
        unsigned t = atomicAdd(ct, 1u);
        if (t == gridDim.x - 1) {
            float seg = atomicAdd(&acc[0], 0.f);   // coherent read
            float kl  = atomicAdd(&acc[1], 0.f);
            float seg_loss = seg / (float)Ns;
            float kl_loss  = KL_W_F * (kl / (float)Ns) * TEMP_F * TEMP_F;
            out[0] = seg_loss + kl_loss;
            out[1] = seg_loss;
            out[2] = kl_loss;
        }
    }
}

extern "C" void kernel_launch(void* const* d_in, const int* in_sizes, int n_in,
                              void* d_out, int out_size, void* d_ws, size_t ws_size,
                              hipStream_t stream)
{
    const float* s_feat  = (const float*)d_in[0];
    const float* t_feat  = (const float*)d_in[1];
    const float* s_coord = (const float*)d_in[2];
    const float* t_coord = (const float*)d_in[3];
    const float* seg_W   = (const float*)d_in[4];
    const float* seg_b   = (const float*)d_in[5];
    const float* seg_tW  = (const float*)d_in[6];
    const float* seg_tb  = (const float*)d_in[7];
    const int*   segment = (const int*)d_in[8];
    float* out = (float*)d_out;

    const int Ns = in_sizes[0] / D;
    const int Nt = in_sizes[1] / D;

    float* tlog = (float*)d_ws;                                        // [Nt*TLP]
    float* slog = tlog + (size_t)Nt * TLP;                             // [Ns*TLP]
    unsigned* cand_ord = (unsigned*)(slog + (size_t)Ns * TLP);         // [NCHUNK*Ns]
    float4* tc4 = (float4*)(cand_ord + (size_t)NCHUNK * Ns);           // [Nt]
    float*  acc = (float*)(tc4 + Nt);                                  // [2]
    unsigned* ct = (unsigned*)(acc + 2);

    const int subs     = (Ns + 256 * SPT - 1) / (256 * SPT);           // 8
    const int nn_total = subs * NCHUNK;                                // 512
    const int ntb      = (Nt + 255) / 256;                             // 64
    const int nsb      = (Ns + 255) / 256;                             // 64

    fat_kernel<<<nn_total + ntb + nsb, 256, 0, stream>>>(
        s_coord, t_coord, t_feat, s_feat, seg_tW, seg_tb, seg_W, seg_b,
        cand_ord, tc4, tlog, slog, acc, ct, Ns, Nt, nn_total, ntb);

    loss_kernel<<<512, 1024, 0, stream>>>(
        s_coord, segment, tlog, slog, cand_ord, tc4, acc, ct, out, Ns);
}